// Round 8
// baseline (268.492 us; speedup 1.0000x reference)
//
#include <hip/hip_runtime.h>

#define SEQ   1024
#define BATCH 512
#define NC    48
#define CH    8

typedef float f2 __attribute__((ext_vector_type(2)));
typedef float f4 __attribute__((ext_vector_type(4)));

__device__ __forceinline__ float rfl(float x) {
    return __int_as_float(__builtin_amdgcn_readfirstlane(__float_as_int(x)));
}
// packed fp32 FMA: acc.lo += a.lo*b.lo ; acc.hi += a.hi*b.hi  (proven R6/R9/R12)
__device__ __forceinline__ void pkfma(f2& acc, f2 a, f2 b) {
    asm("v_pk_fma_f32 %0, %1, %2, %0" : "+v"(acc) : "v"(a), "v"(b));
}
#define LO2(Q) __builtin_shufflevector(Q, Q, 0, 1)
#define HI2(Q) __builtin_shufflevector(Q, Q, 2, 3)

// all-reduce across lane pairs {l,l^16} / {l,l^32} (R8-proven correct):
// v in both operands -> out0+out1 == v[l] + v[l^K] on every lane.
__device__ __forceinline__ float xadd16(float v) {
    auto r = __builtin_amdgcn_permlane16_swap(__float_as_uint(v), __float_as_uint(v), false, false);
    return __uint_as_float(r[0]) + __uint_as_float(r[1]);
}
__device__ __forceinline__ float xadd32(float v) {
    auto r = __builtin_amdgcn_permlane32_swap(__float_as_uint(v), __float_as_uint(v), false, false);
    return __uint_as_float(r[0]) + __uint_as_float(r[1]);
}

// R13 = R12's wave-split (fwd z-chain / bwd u-chain, exact factorization)
// with the per-step broadcast moved off the saturated per-CU LDS pipe.
// R12 diagnosis: 4 waves/CU x 13 DS ops/step x ~12cy/DS = 624cy == measured
// 633cy/step; VALU idle at 11.7%. R13 step: lane (p=lane>>4, q=lane&15)
// owns output cols {q,16+q,32+q}, input rows [12p,12p+12):
//   1 ds_write + 3 ds_read_b128 (4 DS vs 13; disjoint banks across p)
//   + 18 packed MACs + permlane16/32 p-reduce (VALU, idle pipe) + 3 esm muls.
// esm in REGISTERS: 3 global prefetch streams per lane (cols q,16+q,32+q),
// EXP8 per chunk (R9/R12 proven; kills the R10 LDS-esm staging bug class).
__global__ __launch_bounds__(128, 1) void crf_fwd(
    const float* __restrict__ scores,   // [SEQ][BATCH][NC]
    const int*   __restrict__ target,   // [SEQ][BATCH]
    const int*   __restrict__ lengths,  // [BATCH]
    const float* __restrict__ trans,    // [NC][NC]
    float* __restrict__ out)            // [2*BATCH]: X, then X - logZ
{
    const int b    = blockIdx.x;
    const int tid  = threadIdx.x;
    const int lane = tid & 63;
    const int wid  = tid >> 6;
    const int q    = lane & 15;
    const int p    = lane >> 4;
    const int L    = lengths[b];                       // uniform within block
    const float LOG2E = 1.4426950408889634f;
    const float LN2   = 0.6931471805599453f;
    const size_t TS = (size_t)BATCH * NC;
    const float* sp0 = scores + (size_t)b * NC + q;    // cols q, 16+q, 32+q

    __shared__ __align__(16) float zbF[64];   // wave 0 broadcast buffer
    __shared__ __align__(16) float zbB[64];   // wave 1 broadcast buffer
    __shared__ float ures[64];                // wave1 -> wave0 handoff
    __shared__ float xpart[2];
    __shared__ float shSB;

    // 3-stream chunk prefetch: lane's 3 owned columns at 8 consecutive t
    #define PREFETCH3(b0, b1, b2, tbase) do { \
        _Pragma("unroll") \
        for (int j_ = 0; j_ < CH; ++j_) { \
            int tt_ = (tbase) + j_; if (tt_ > SEQ - 1) tt_ = SEQ - 1; \
            const float* r_ = sp0 + (size_t)tt_ * TS; \
            (b0)[j_] = r_[0]; (b1)[j_] = r_[16]; (b2)[j_] = r_[32]; \
        } } while (0)
    #define EXP83(b0, b1, b2) do { _Pragma("unroll") \
        for (int k_ = 0; k_ < CH; ++k_) { \
            (b0)[k_] = __builtin_amdgcn_exp2f((b0)[k_] * LOG2E); \
            (b1)[k_] = __builtin_amdgcn_exp2f((b1)[k_] * LOG2E); \
            (b2)[k_] = __builtin_amdgcn_exp2f((b2)[k_] * LOG2E); \
        } } while (0)

    // ---- target path score X (parallel over t across 128 threads) ----
    float x = 0.f;
    #pragma unroll 2
    for (int t = tid; t < L; t += 128) {
        int cur = target[t * BATCH + b];
        float e = scores[(size_t)t * TS + (size_t)b * NC + cur];
        float tr = 0.f;
        if (t > 0) {
            int prev = target[(t - 1) * BATCH + b];
            tr = trans[prev * NC + cur];
        }
        x += e + tr;
    }
    #pragma unroll
    for (int k = 32; k >= 1; k >>= 1) x += __shfl_xor(x, k, 64);
    if (lane == 0) xpart[wid] = x;

    float v0 = 1.f, v1 = 1.f, v2 = 1.f, S = 0.f;   // chain state (z or u), replicated over p

    // exact pow2 rescale (logZ-invariant; lane 0 holds state[0])
    #define RS() do { \
        int e_ = (__builtin_amdgcn_readfirstlane(__float_as_int(v0)) >> 23) & 255; \
        float sc_ = __int_as_float((254 - e_) << 23); \
        v0 *= sc_; v1 *= sc_; v2 *= sc_; S += (float)(e_ - 127); } while (0)

    if (wid == 0) {
        // ================= forward: z_t = D_t E^T z_{t-1}, t = 1..min(L,512)-1 =====
        float f0A[CH], f1A[CH], f2A[CH], f0B[CH], f1B[CH], f2B[CH];
        PREFETCH3(f0A, f1A, f2A, 0);
        PREFETCH3(f0B, f1B, f2B, CH);

        // EP[c][k] = {E[12p+2k][16c+q], E[12p+2k+1][16c+q]},  E = exp(T)
        f2 EP[3][6];
        #pragma unroll
        for (int c = 0; c < 3; ++c) {
            int col = 16*c + q;
            #pragma unroll
            for (int k = 0; k < 6; ++k) {
                EP[c][k].x = __builtin_amdgcn_exp2f(trans[(12*p + 2*k)*NC + col] * LOG2E);
                EP[c][k].y = __builtin_amdgcn_exp2f(trans[(12*p + 2*k + 1)*NC + col] * LOG2E);
                asm("" : "+v"(EP[c][k]));   // pin: no remat
            }
        }

        // init from raw chunk-0 values (before EXP83)
        float i0 = f0A[0], i1 = f1A[0], i2 = f2A[0];
        float s00 = rfl(i0);                 // lane 0: s_0[0]
        v0 = __builtin_amdgcn_exp2f((i0 - s00) * LOG2E);
        v1 = __builtin_amdgcn_exp2f((i1 - s00) * LOG2E);
        v2 = __builtin_amdgcn_exp2f((i2 - s00) * LOG2E);
        S  = s00 * LOG2E;
        EXP83(f0A, f1A, f2A);

        #define FSTEP_CORE(e0v, e1v, e2v, UPD) do { \
            float vw_ = v0; vw_ = (p == 1) ? v1 : vw_; vw_ = (p == 2) ? v2 : vw_; \
            zbF[lane] = vw_; \
            asm volatile("" ::: "memory"); \
            const f4* zq_ = (const f4*)(zbF + 12*p); \
            f4 Z0 = zq_[0], Z1 = zq_[1], Z2 = zq_[2]; \
            f2 a0_ = LO2(Z0)*EP[0][0], a1_ = LO2(Z0)*EP[1][0], a2_ = LO2(Z0)*EP[2][0]; \
            pkfma(a0_, HI2(Z0), EP[0][1]); pkfma(a1_, HI2(Z0), EP[1][1]); pkfma(a2_, HI2(Z0), EP[2][1]); \
            pkfma(a0_, LO2(Z1), EP[0][2]); pkfma(a1_, LO2(Z1), EP[1][2]); pkfma(a2_, LO2(Z1), EP[2][2]); \
            pkfma(a0_, HI2(Z1), EP[0][3]); pkfma(a1_, HI2(Z1), EP[1][3]); pkfma(a2_, HI2(Z1), EP[2][3]); \
            pkfma(a0_, LO2(Z2), EP[0][4]); pkfma(a1_, LO2(Z2), EP[1][4]); pkfma(a2_, LO2(Z2), EP[2][4]); \
            pkfma(a0_, HI2(Z2), EP[0][5]); pkfma(a1_, HI2(Z2), EP[1][5]); pkfma(a2_, HI2(Z2), EP[2][5]); \
            float s0_ = a0_.x + a0_.y, s1_ = a1_.x + a1_.y, s2_ = a2_.x + a2_.y; \
            s0_ = xadd16(s0_); s1_ = xadd16(s1_); s2_ = xadd16(s2_); \
            s0_ = xadd32(s0_); s1_ = xadd32(s1_); s2_ = xadd32(s2_); \
            float nv0_ = s0_ * (e0v), nv1_ = s1_ * (e1v), nv2_ = s2_ * (e2v); \
            UPD; \
        } while (0)
        #define FSTEPU(b0,b1,b2,i)     FSTEP_CORE((b0)[i],(b1)[i],(b2)[i], { v0=nv0_; v1=nv1_; v2=nv2_; })
        #define FSTEPG(b0,b1,b2,i,tb)  FSTEP_CORE((b0)[i],(b1)[i],(b2)[i], { if (((tb)+(i)) < L) { v0=nv0_; v1=nv1_; v2=nv2_; } })
        #define FCHUNK8U(b0,b1,b2) do { \
            FSTEPU(b0,b1,b2,0); FSTEPU(b0,b1,b2,1); FSTEPU(b0,b1,b2,2); FSTEPU(b0,b1,b2,3); RS(); \
            FSTEPU(b0,b1,b2,4); FSTEPU(b0,b1,b2,5); FSTEPU(b0,b1,b2,6); FSTEPU(b0,b1,b2,7); RS(); } while (0)
        #define FCHUNK8G(b0,b1,b2,tb) do { \
            FSTEPG(b0,b1,b2,0,tb); FSTEPG(b0,b1,b2,1,tb); FSTEPG(b0,b1,b2,2,tb); FSTEPG(b0,b1,b2,3,tb); RS(); \
            FSTEPG(b0,b1,b2,4,tb); FSTEPG(b0,b1,b2,5,tb); FSTEPG(b0,b1,b2,6,tb); FSTEPG(b0,b1,b2,7,tb); RS(); } while (0)

        // prologue: steps 1..7 (guarded; L may be small)
        FSTEPG(f0A,f1A,f2A,1,0); FSTEPG(f0A,f1A,f2A,2,0); FSTEPG(f0A,f1A,f2A,3,0); RS();
        FSTEPG(f0A,f1A,f2A,4,0); FSTEPG(f0A,f1A,f2A,5,0); FSTEPG(f0A,f1A,f2A,6,0); FSTEPG(f0A,f1A,f2A,7,0); RS();

        const int Lf = (L < 512) ? L : 512;   // forward stops at z_511
        int t0 = CH;
        int useB = 1;
        while (t0 + CH <= Lf) {
            if (useB) { PREFETCH3(f0A,f1A,f2A, t0 + CH); EXP83(f0B,f1B,f2B); FCHUNK8U(f0B,f1B,f2B); }
            else      { PREFETCH3(f0B,f1B,f2B, t0 + CH); EXP83(f0A,f1A,f2A); FCHUNK8U(f0A,f1A,f2A); }
            useB ^= 1;
            t0 += CH;
        }
        if (t0 < Lf) {
            if (useB) { EXP83(f0B,f1B,f2B); FCHUNK8G(f0B,f1B,f2B, t0); }
            else      { EXP83(f0A,f1A,f2A); FCHUNK8G(f0A,f1A,f2A, t0); }
        }
    } else {
        // ================= backward: u_t = E (esm_t * u_{t+1}), t = 1023..512 ====
        float b0A[CH], b1A[CH], b2A[CH], b0B[CH], b1B[CH], b2B[CH];
        // EB[c][k] = {E[16c+q][12p+2k], E[16c+q][12p+2k+1]}
        f2 EB[3][6];
        #pragma unroll
        for (int c = 0; c < 3; ++c) {
            int row = 16*c + q;
            #pragma unroll
            for (int k = 0; k < 6; ++k) {
                EB[c][k].x = __builtin_amdgcn_exp2f(trans[row*NC + 12*p + 2*k] * LOG2E);
                EB[c][k].y = __builtin_amdgcn_exp2f(trans[row*NC + 12*p + 2*k + 1] * LOG2E);
                asm("" : "+v"(EB[c][k]));
            }
        }

        #define BSTEP_CORE(e0v, e1v, e2v, UPD) do { \
            float w0_ = v0 * (e0v), w1_ = v1 * (e1v), w2_ = v2 * (e2v); \
            float vw_ = w0_; vw_ = (p == 1) ? w1_ : vw_; vw_ = (p == 2) ? w2_ : vw_; \
            zbB[lane] = vw_; \
            asm volatile("" ::: "memory"); \
            const f4* zq_ = (const f4*)(zbB + 12*p); \
            f4 Z0 = zq_[0], Z1 = zq_[1], Z2 = zq_[2]; \
            f2 a0_ = LO2(Z0)*EB[0][0], a1_ = LO2(Z0)*EB[1][0], a2_ = LO2(Z0)*EB[2][0]; \
            pkfma(a0_, HI2(Z0), EB[0][1]); pkfma(a1_, HI2(Z0), EB[1][1]); pkfma(a2_, HI2(Z0), EB[2][1]); \
            pkfma(a0_, LO2(Z1), EB[0][2]); pkfma(a1_, LO2(Z1), EB[1][2]); pkfma(a2_, LO2(Z1), EB[2][2]); \
            pkfma(a0_, HI2(Z1), EB[0][3]); pkfma(a1_, HI2(Z1), EB[1][3]); pkfma(a2_, HI2(Z1), EB[2][3]); \
            pkfma(a0_, LO2(Z2), EB[0][4]); pkfma(a1_, LO2(Z2), EB[1][4]); pkfma(a2_, LO2(Z2), EB[2][4]); \
            pkfma(a0_, HI2(Z2), EB[0][5]); pkfma(a1_, HI2(Z2), EB[1][5]); pkfma(a2_, HI2(Z2), EB[2][5]); \
            float s0_ = a0_.x + a0_.y, s1_ = a1_.x + a1_.y, s2_ = a2_.x + a2_.y; \
            s0_ = xadd16(s0_); s1_ = xadd16(s1_); s2_ = xadd16(s2_); \
            float nv0_ = xadd32(s0_), nv1_ = xadd32(s1_), nv2_ = xadd32(s2_); \
            UPD; \
        } while (0)
        #define BSTEPU(b0,b1,b2,i)     BSTEP_CORE((b0)[i],(b1)[i],(b2)[i], { v0=nv0_; v1=nv1_; v2=nv2_; })
        #define BSTEPG(b0,b1,b2,i,tb)  BSTEP_CORE((b0)[i],(b1)[i],(b2)[i], { if (((tb)+(i)) < L) { v0=nv0_; v1=nv1_; v2=nv2_; } })
        #define BCHUNK8U(b0,b1,b2) do { \
            BSTEPU(b0,b1,b2,7); BSTEPU(b0,b1,b2,6); BSTEPU(b0,b1,b2,5); BSTEPU(b0,b1,b2,4); RS(); \
            BSTEPU(b0,b1,b2,3); BSTEPU(b0,b1,b2,2); BSTEPU(b0,b1,b2,1); BSTEPU(b0,b1,b2,0); RS(); } while (0)

        if (L > 512) {                       // else: u stays all-ones exactly
            const int chi = (L - 1) >> 3;    // top active chunk, in [64,127]
            const int tbt = chi * CH;
            PREFETCH3(b0A,b1A,b2A, tbt);
            PREFETCH3(b0B,b1B,b2B, tbt - CH);
            EXP83(b0A,b1A,b2A);
            // top chunk guarded (t >= L frozen), steps descend
            BSTEPG(b0A,b1A,b2A,7,tbt); BSTEPG(b0A,b1A,b2A,6,tbt);
            BSTEPG(b0A,b1A,b2A,5,tbt); BSTEPG(b0A,b1A,b2A,4,tbt); RS();
            BSTEPG(b0A,b1A,b2A,3,tbt); BSTEPG(b0A,b1A,b2A,2,tbt);
            BSTEPG(b0A,b1A,b2A,1,tbt); BSTEPG(b0A,b1A,b2A,0,tbt); RS();
            PREFETCH3(b0A,b1A,b2A, tbt - 2*CH);
            int ck = chi - 1;
            int useB2 = 1;
            while (ck >= 64) {               // unguarded chunks down to t=512
                if (useB2) { EXP83(b0B,b1B,b2B); BCHUNK8U(b0B,b1B,b2B); PREFETCH3(b0B,b1B,b2B, (ck-2)*CH); }
                else       { EXP83(b0A,b1A,b2A); BCHUNK8U(b0A,b1A,b2A); PREFETCH3(b0A,b1A,b2A, (ck-2)*CH); }
                useB2 ^= 1;
                --ck;
            }
        }
        if (p == 0) { ures[q] = v0; ures[16 + q] = v1; ures[32 + q] = v2; }
        if (lane == 0) shSB = S;
    }

    __syncthreads();

    // ---- combine (wave 0): logZ = ln2 * (log2( sum_j z[j]*u[j] ) + SF + SB) ----
    if (wid == 0) {
        float pr = v0 * ures[q] + v1 * ures[16 + q] + v2 * ures[32 + q];
        pr += __shfl_xor(pr, 1, 64);
        pr += __shfl_xor(pr, 2, 64);
        pr += __shfl_xor(pr, 4, 64);
        pr += __shfl_xor(pr, 8, 64);
        float logZ = (__builtin_amdgcn_logf(pr) + S + shSB) * LN2;
        if (lane == 0) {
            float X = xpart[0] + xpart[1];
            out[b]         = X;          // output 0: X
            out[BATCH + b] = X - logZ;   // output 1: X - logZ
        }
    }
}

extern "C" void kernel_launch(void* const* d_in, const int* in_sizes, int n_in,
                              void* d_out, int out_size, void* d_ws, size_t ws_size,
                              hipStream_t stream) {
    const float* scores  = (const float*)d_in[0];
    const int*   target  = (const int*)d_in[1];
    const int*   lengths = (const int*)d_in[2];
    const float* trans   = (const float*)d_in[3];
    float* out = (float*)d_out;
    crf_fwd<<<BATCH, 128, 0, stream>>>(scores, target, lengths, trans, out);
}

// Round 9
// 217.657 us; speedup vs baseline: 1.2336x; 1.2336x over previous
//
#include <hip/hip_runtime.h>

#define SEQ   1024
#define BATCH 512
#define NC    48
#define CH    8

typedef float f2 __attribute__((ext_vector_type(2)));
typedef float f4 __attribute__((ext_vector_type(4)));

__device__ __forceinline__ float rfl(float x) {
    return __int_as_float(__builtin_amdgcn_readfirstlane(__float_as_int(x)));
}
// packed fp32 FMA: acc.lo += a.lo*b.lo ; acc.hi += a.hi*b.hi  (proven R6/R9/R12)
__device__ __forceinline__ void pkfma(f2& acc, f2 a, f2 b) {
    asm("v_pk_fma_f32 %0, %1, %2, %0" : "+v"(acc) : "v"(a), "v"(b));
}
#define LO2(Q) __builtin_shufflevector(Q, Q, 0, 1)
#define HI2(Q) __builtin_shufflevector(Q, Q, 2, 3)

// R14 = R12's verified fwd/bwd wave-split, re-packed so every wave gets its
// own SIMD. Diagnosis across R9/R12/R13: waves are placed on SIMD =
// wave_id_in_workgroup mod 4, so 2-wave blocks at 2 blocks/CU stack both
// wave0s on SIMD0 (VALUBusy arithmetic matches 2-waves-per-busy-SIMD
// EXACTLY in all three rounds: 11.7/17.9/8.5%). Issue-port sharing + stall
// serialization = R12's +208cy/step. Here: 256-thread blocks, 2 batch
// elements each; wave w -> SIMD w; wave e = fwd(elem e), wave 2+e = bwd(elem e).
//   fwd:  z_t = D_t E^T z_{t-1}, t = 1..min(L,512)-1     (R9 step, proven)
//   bwd:  u_t = E D_t u_{t+1},   t = 1023..512, u=1 init (frozen t>=L = identity)
//   logZ = log2(u_512 . z_511) + SF + SB                  (exact, R12-verified)
// Step mechanics byte-identical to R12. Clean A/B on wave placement.
__global__ __launch_bounds__(256, 1) void crf_fwd(
    const float* __restrict__ scores,   // [SEQ][BATCH][NC]
    const int*   __restrict__ target,   // [SEQ][BATCH]
    const int*   __restrict__ lengths,  // [BATCH]
    const float* __restrict__ trans,    // [NC][NC]
    float* __restrict__ out)            // [2*BATCH]: X, then X - logZ
{
    const int tid  = threadIdx.x;
    const int lane = tid & 63;
    const int w    = tid >> 6;          // wave 0..3 -> SIMD w
    const int e    = w & 1;             // element within block
    const int dir  = w >> 1;            // 0 = forward wave, 1 = backward wave
    const int b    = blockIdx.x * 2 + e;
    const int jc   = (lane < NC) ? lane : (NC - 1);   // lanes 48-63 mirror idx 47
    const int L    = lengths[b];                       // uniform within wave
    const float LOG2E = 1.4426950408889634f;
    const float LN2   = 0.6931471805599453f;
    const size_t TS = (size_t)BATCH * NC;
    const float* sp = scores + (size_t)b * NC + jc;

    __shared__ __align__(16) float zball[4][64];  // per-wave broadcast buffer
    __shared__ float ures[2][64];                 // bwd -> fwd handoff per element
    __shared__ float xpart[4];
    __shared__ float shSBa[2];
    float* zb = zball[w];

    #define PREFETCH(buf, tbase) do { \
        _Pragma("unroll") \
        for (int j_ = 0; j_ < CH; ++j_) { \
            int tt_ = (tbase) + j_; if (tt_ > SEQ - 1) tt_ = SEQ - 1; \
            (buf)[j_] = sp[(size_t)tt_ * TS]; \
        } } while (0)
    #define EXP8(buf) do { _Pragma("unroll") \
        for (int k_ = 0; k_ < CH; ++k_) (buf)[k_] = __builtin_amdgcn_exp2f((buf)[k_] * LOG2E); } while (0)

    // ---- target path score X: fwd wave covers [0,min(L,512)), bwd [512,L) ----
    {
        float x = 0.f;
        const int tbeg = dir ? 512 : 0;
        const int tend = dir ? L : (L < 512 ? L : 512);
        #pragma unroll 2
        for (int t = tbeg + lane; t < tend; t += 64) {
            int cur = target[t * BATCH + b];
            float ev = scores[(size_t)t * TS + (size_t)b * NC + cur];
            float tr = 0.f;
            if (t > 0) {
                int prev = target[(t - 1) * BATCH + b];
                tr = trans[prev * NC + cur];
            }
            x += ev + tr;
        }
        #pragma unroll
        for (int k = 32; k >= 1; k >>= 1) x += __shfl_xor(x, k, 64);
        if (lane == 0) xpart[w] = x;
    }

    float z = 0.f, SF = 0.f;   // fwd results (read after barrier)

    if (dir == 0) {
        // ================= forward chain (R12 verbatim, zb buffer) =========
        float fA[CH], fB[CH];
        PREFETCH(fA, 0); PREFETCH(fB, CH);
        f2 ep[24];                      // ep[k] = {e^T[2k][jc], e^T[2k+1][jc]}
        #pragma unroll
        for (int k = 0; k < 24; ++k) {
            ep[k].x = __builtin_amdgcn_exp2f(trans[(2*k)*NC + jc] * LOG2E);
            ep[k].y = __builtin_amdgcn_exp2f(trans[(2*k+1)*NC + jc] * LOG2E);
            asm("" : "+v"(ep[k]));      // pin: no remat
        }
        float sv = fA[0];
        float s00 = rfl(sv);
        z  = __builtin_amdgcn_exp2f((sv - s00) * LOG2E);
        SF = s00 * LOG2E;
        EXP8(fA);

        #define RSF() do { \
            int e_ = (__builtin_amdgcn_readfirstlane(__float_as_int(z)) >> 23) & 255; \
            z *= __int_as_float((254 - e_) << 23); SF += (float)(e_ - 127); } while (0)

        #define FSTEP_CORE(esmv, ZUPD) do { \
            zb[lane] = z; \
            asm volatile("" ::: "memory"); \
            const f4* zq_ = (const f4*)zb; \
            f4 Q0=zq_[0], Q1=zq_[1], Q2=zq_[2],  Q3=zq_[3]; \
            f4 Q4=zq_[4], Q5=zq_[5], Q6=zq_[6],  Q7=zq_[7]; \
            f4 Q8=zq_[8], Q9=zq_[9], Q10=zq_[10], Q11=zq_[11]; \
            f2 k0 = LO2(Q0)*ep[0],  k1 = HI2(Q0)*ep[1]; \
            f2 k2 = LO2(Q1)*ep[2],  k3 = HI2(Q1)*ep[3]; \
            pkfma(k0, LO2(Q2),  ep[4]);   pkfma(k1, HI2(Q2),  ep[5]); \
            pkfma(k2, LO2(Q3),  ep[6]);   pkfma(k3, HI2(Q3),  ep[7]); \
            pkfma(k0, LO2(Q4),  ep[8]);   pkfma(k1, HI2(Q4),  ep[9]); \
            pkfma(k2, LO2(Q5),  ep[10]);  pkfma(k3, HI2(Q5),  ep[11]); \
            pkfma(k0, LO2(Q6),  ep[12]);  pkfma(k1, HI2(Q6),  ep[13]); \
            pkfma(k2, LO2(Q7),  ep[14]);  pkfma(k3, HI2(Q7),  ep[15]); \
            pkfma(k0, LO2(Q8),  ep[16]);  pkfma(k1, HI2(Q8),  ep[17]); \
            pkfma(k2, LO2(Q9),  ep[18]);  pkfma(k3, HI2(Q9),  ep[19]); \
            pkfma(k0, LO2(Q10), ep[20]);  pkfma(k1, HI2(Q10), ep[21]); \
            pkfma(k2, LO2(Q11), ep[22]);  pkfma(k3, HI2(Q11), ep[23]); \
            f2 kk = (k0 + k1) + (k2 + k3); \
            float znew_ = (kk.x + kk.y) * (esmv); \
            ZUPD; \
        } while (0)
        #define FSTEPU(buf, i)      FSTEP_CORE((buf)[i], z = znew_)
        #define FSTEPG(buf, i, tb)  FSTEP_CORE((buf)[i], if (((tb)+(i)) < L) z = znew_)
        #define FCHUNK8U(buf) do { \
            FSTEPU(buf,0); FSTEPU(buf,1); FSTEPU(buf,2); FSTEPU(buf,3); RSF(); \
            FSTEPU(buf,4); FSTEPU(buf,5); FSTEPU(buf,6); FSTEPU(buf,7); RSF(); } while (0)
        #define FCHUNK8G(buf, tb) do { \
            FSTEPG(buf,0,tb); FSTEPG(buf,1,tb); FSTEPG(buf,2,tb); FSTEPG(buf,3,tb); RSF(); \
            FSTEPG(buf,4,tb); FSTEPG(buf,5,tb); FSTEPG(buf,6,tb); FSTEPG(buf,7,tb); RSF(); } while (0)

        // prologue: steps 1..7 (guarded; L may be small)
        FSTEPG(fA,1,0); FSTEPG(fA,2,0); FSTEPG(fA,3,0); RSF();
        FSTEPG(fA,4,0); FSTEPG(fA,5,0); FSTEPG(fA,6,0); FSTEPG(fA,7,0); RSF();

        const int Lf = (L < 512) ? L : 512;   // forward stops at z_511
        int t0 = CH;
        int useB = 1;
        while (t0 + CH <= Lf) {
            if (useB) { PREFETCH(fA, t0 + CH); EXP8(fB); FCHUNK8U(fB); }
            else      { PREFETCH(fB, t0 + CH); EXP8(fA); FCHUNK8U(fA); }
            useB ^= 1;
            t0 += CH;
        }
        if (t0 < Lf) {
            if (useB) { EXP8(fB); FCHUNK8G(fB, t0); }
            else      { EXP8(fA); FCHUNK8G(fA, t0); }
        }
    } else {
        // ================= backward chain (R12 verbatim, zb buffer) ========
        float bA[CH], bB[CH];
        f2 eb[24];                      // eb[k] = {e^T[jc][2k], e^T[jc][2k+1]}  (row jc)
        #pragma unroll
        for (int k = 0; k < 24; ++k) {
            eb[k].x = __builtin_amdgcn_exp2f(trans[jc*NC + 2*k] * LOG2E);
            eb[k].y = __builtin_amdgcn_exp2f(trans[jc*NC + 2*k + 1] * LOG2E);
            asm("" : "+v"(eb[k]));
        }
        float u = 1.f, SB = 0.f;

        #define RSB() do { \
            int e_ = (__builtin_amdgcn_readfirstlane(__float_as_int(u)) >> 23) & 255; \
            u *= __int_as_float((254 - e_) << 23); SB += (float)(e_ - 127); } while (0)

        #define BSTEP_CORE(esmv, UUPD) do { \
            float vw_ = u * (esmv); \
            zb[lane] = vw_; \
            asm volatile("" ::: "memory"); \
            const f4* bq_ = (const f4*)zb; \
            f4 Q0=bq_[0], Q1=bq_[1], Q2=bq_[2],  Q3=bq_[3]; \
            f4 Q4=bq_[4], Q5=bq_[5], Q6=bq_[6],  Q7=bq_[7]; \
            f4 Q8=bq_[8], Q9=bq_[9], Q10=bq_[10], Q11=bq_[11]; \
            f2 k0 = LO2(Q0)*eb[0],  k1 = HI2(Q0)*eb[1]; \
            f2 k2 = LO2(Q1)*eb[2],  k3 = HI2(Q1)*eb[3]; \
            pkfma(k0, LO2(Q2),  eb[4]);   pkfma(k1, HI2(Q2),  eb[5]); \
            pkfma(k2, LO2(Q3),  eb[6]);   pkfma(k3, HI2(Q3),  eb[7]); \
            pkfma(k0, LO2(Q4),  eb[8]);   pkfma(k1, HI2(Q4),  eb[9]); \
            pkfma(k2, LO2(Q5),  eb[10]);  pkfma(k3, HI2(Q5),  eb[11]); \
            pkfma(k0, LO2(Q6),  eb[12]);  pkfma(k1, HI2(Q6),  eb[13]); \
            pkfma(k2, LO2(Q7),  eb[14]);  pkfma(k3, HI2(Q7),  eb[15]); \
            pkfma(k0, LO2(Q8),  eb[16]);  pkfma(k1, HI2(Q8),  eb[17]); \
            pkfma(k2, LO2(Q9),  eb[18]);  pkfma(k3, HI2(Q9),  eb[19]); \
            pkfma(k0, LO2(Q10), eb[20]);  pkfma(k1, HI2(Q10), eb[21]); \
            pkfma(k2, LO2(Q11), eb[22]);  pkfma(k3, HI2(Q11), eb[23]); \
            f2 kk = (k0 + k1) + (k2 + k3); \
            float unew_ = kk.x + kk.y; \
            UUPD; \
        } while (0)
        #define BSTEPU(buf, i)      BSTEP_CORE((buf)[i], u = unew_)
        #define BSTEPG(buf, i, tb)  BSTEP_CORE((buf)[i], if (((tb)+(i)) < L) u = unew_)
        #define BCHUNK8U(buf) do { \
            BSTEPU(buf,7); BSTEPU(buf,6); BSTEPU(buf,5); BSTEPU(buf,4); RSB(); \
            BSTEPU(buf,3); BSTEPU(buf,2); BSTEPU(buf,1); BSTEPU(buf,0); RSB(); } while (0)

        if (L > 512) {                       // else: u stays all-ones exactly
            const int chi = (L - 1) >> 3;    // top active chunk, in [64,127]
            const int tbt = chi * CH;
            PREFETCH(bA, tbt); PREFETCH(bB, tbt - CH);
            EXP8(bA);
            // top chunk guarded (t >= L frozen), steps descend
            BSTEPG(bA,7,tbt); BSTEPG(bA,6,tbt); BSTEPG(bA,5,tbt); BSTEPG(bA,4,tbt); RSB();
            BSTEPG(bA,3,tbt); BSTEPG(bA,2,tbt); BSTEPG(bA,1,tbt); BSTEPG(bA,0,tbt); RSB();
            PREFETCH(bA, tbt - 2*CH);
            int ck = chi - 1;
            int useB2 = 1;
            while (ck >= 64) {               // unguarded full chunks down to t=512
                if (useB2) { EXP8(bB); BCHUNK8U(bB); PREFETCH(bB, (ck-2)*CH); }
                else       { EXP8(bA); BCHUNK8U(bA); PREFETCH(bA, (ck-2)*CH); }
                useB2 ^= 1;
                --ck;
            }
        }
        ures[e][lane] = u;                   // cols >= 48 never read
        if (lane == 0) shSBa[e] = SB;
    }

    __syncthreads();

    // ---- combine (fwd waves): logZ = ln2*(log2(sum_j z[j]*u[j]) + SF + SB) ----
    if (dir == 0) {
        float pr = (lane < NC) ? z * ures[e][lane] : 0.f;
        #pragma unroll
        for (int k = 32; k >= 1; k >>= 1) pr += __shfl_xor(pr, k, 64);
        float logZ = (__builtin_amdgcn_logf(pr) + SF + shSBa[e]) * LN2;
        if (lane == 0) {
            float X = xpart[e] + xpart[2 + e];
            out[b]         = X;          // output 0: X
            out[BATCH + b] = X - logZ;   // output 1: X - logZ
        }
    }
}

extern "C" void kernel_launch(void* const* d_in, const int* in_sizes, int n_in,
                              void* d_out, int out_size, void* d_ws, size_t ws_size,
                              hipStream_t stream) {
    const float* scores  = (const float*)d_in[0];
    const int*   target  = (const int*)d_in[1];
    const int*   lengths = (const int*)d_in[2];
    const float* trans   = (const float*)d_in[3];
    float* out = (float*)d_out;
    crf_fwd<<<BATCH / 2, 256, 0, stream>>>(scores, target, lengths, trans, out);
}